// Round 7
// baseline (23.536 us; speedup 1.0000x reference)
//
#include <hip/hip_runtime.h>

#define B_SZ 512
#define V_SZ 1024
#define K_SZ 64
#define C_SZ 2048
#define A_SZ 128

#define LOG2E 1.4426950408889634f

// ---------------------------------------------------------------------------
// Kernel 1: alpha = exp(xs@Wa+ba), beta = exp(xs@Wb+bb),
//           new_kappa = prev_kappa + exp(xs@Wk+bk)
// 128 blocks x 768 threads (12 waves), 4 batch rows per block.
// Wave w: matrix m = w>>2, v-quarter q = w&3, lane = k. ONE W-stream per
// wave (1 global load/iter), 4 x-rows interleaved in LDS as float4
// (1 ds_read_b128/iter), 4 FMAs. L2 W-traffic: 128 x 786KB = 100MB
// (~3us floor). Epilogue: exactly 768 items = 3 mats x 4 rows x 64 k.
// ---------------------------------------------------------------------------
__global__ __launch_bounds__(768) void gw_abk(
    const float* __restrict__ x,
    const float* __restrict__ prev_kappa,
    const float* __restrict__ Wa, const float* __restrict__ ba,
    const float* __restrict__ Wb, const float* __restrict__ bb,
    const float* __restrict__ Wk, const float* __restrict__ bk,
    float* __restrict__ ws_alpha, float* __restrict__ ws_beta,
    float* __restrict__ ws_kappa, float* __restrict__ out_kappa) {
  __shared__ float4 xs4[V_SZ];            // 16KB: {r0[v], r1[v], r2[v], r3[v]}
  __shared__ float part[12][4][K_SZ];     // 12KB: [wave][row][k]

  const int tid = threadIdx.x;
  const int b0 = blockIdx.x * 4;

  {
    const float* xr = x + (size_t)b0 * V_SZ;
    for (int i = tid; i < V_SZ; i += 768)   // 4 coalesced row sweeps
      xs4[i] = make_float4(xr[i], xr[V_SZ + i],
                           xr[2 * V_SZ + i], xr[3 * V_SZ + i]);
  }
  __syncthreads();

  const int w = tid >> 6;     // wave 0..11
  const int m = w >> 2;       // 0=alpha, 1=beta, 2=kappa
  const int q = w & 3;        // v-quarter
  const int k = tid & 63;
  const float* __restrict__ Wm = (m == 0) ? Wa : (m == 1) ? Wb : Wk;

  float a0 = 0.f, a1 = 0.f, a2 = 0.f, a3 = 0.f;
  const int v0 = q * 256;
#pragma unroll 8
  for (int v = v0; v < v0 + 256; ++v) {
    float wv = Wm[v * K_SZ + k];    // 256B coalesced, single stream
    float4 xv = xs4[v];             // one ds_read_b128, wave-uniform addr
    a0 = fmaf(xv.x, wv, a0);
    a1 = fmaf(xv.y, wv, a1);
    a2 = fmaf(xv.z, wv, a2);
    a3 = fmaf(xv.w, wv, a3);
  }
  part[w][0][k] = a0;
  part[w][1][k] = a1;
  part[w][2][k] = a2;
  part[w][3][k] = a3;
  __syncthreads();

  // exactly 768 work items: mm = tid>>8, r = (tid>>6)&3, kk = tid&63
  {
    const int mm = tid >> 8;
    const int r = (tid >> 6) & 3;
    const int kk = tid & 63;
    float s = part[mm * 4 + 0][r][kk] + part[mm * 4 + 1][r][kk] +
              part[mm * 4 + 2][r][kk] + part[mm * 4 + 3][r][kk];
    const float bias = ((mm == 0) ? ba : (mm == 1) ? bb : bk)[kk];
    const float e = expf(s + bias);
    const int idx = (b0 + r) * K_SZ + kk;
    if (mm == 0) {
      ws_alpha[idx] = e;
    } else if (mm == 1) {
      ws_beta[idx] = e;
    } else {
      float nk = prev_kappa[idx] + e;
      ws_kappa[idx] = nk;
      out_kappa[idx] = nk;
    }
  }
}

// ---------------------------------------------------------------------------
// Kernel 2 (verbatim, proven): one block (512 threads) per batch row.
//  1) conservative cutoff CL: for c >= CL every Gaussian term <= 2^-150
//     -> phi[c] == 0 exactly (vs absmax threshold ~6.9).
//  2) phi[c] for c < CL (exact), zeros beyond; write phi output.
//  3) window = phi[0:CL) @ text[0:CL)  -- reads only CL rows of text.
// ---------------------------------------------------------------------------
__global__ __launch_bounds__(512) void gw_phi_window(
    const float* __restrict__ text,
    const float* __restrict__ ws_alpha, const float* __restrict__ ws_beta,
    const float* __restrict__ ws_kappa,
    float* __restrict__ out_phi, float* __restrict__ out_window) {
  __shared__ float al[K_SZ];
  __shared__ float bn[K_SZ];     // -log2(e) * beta  (exp2 scale)
  __shared__ float kap[K_SZ];
  __shared__ float bnd[K_SZ];
  __shared__ int cl_s;
  __shared__ float phi_s[C_SZ];
  __shared__ float4 red[16][32];

  const int tid = threadIdx.x;
  const int b = blockIdx.x;

  if (tid < K_SZ) {
    float a  = ws_alpha[b * K_SZ + tid];
    float be = ws_beta[b * K_SZ + tid];
    float kp = ws_kappa[b * K_SZ + tid];
    al[tid] = a;
    bn[tid] = -LOG2E * be;
    kap[tid] = kp;
    // solve LOG2E*be*d^2 >= 150 + max(0, log2(a))  ->  term <= 2^-150
    float num = 150.f + fmaxf(0.f, log2f(a));
    bnd[tid] = kp + sqrtf(num / (LOG2E * be));
  }
  __syncthreads();

  if (tid == 0) {
    float m = 0.f;
    for (int i = 0; i < K_SZ; ++i) m = fmaxf(m, bnd[i]);
    m = fminf(m, (float)C_SZ);        // also sanitizes inf -> full compute
    int cl = (int)m + 1;
    cl = (cl + 15) & ~15;             // multiple of 16 for the window loop
    if (cl > C_SZ) cl = C_SZ;
    cl_s = cl;
  }
  __syncthreads();
  const int CL = cl_s;

  // ---- phi for c < CL ----
  for (int c = tid; c < CL; c += 512) {
    float cf = (float)c;
    float s = 0.f;
#pragma unroll
    for (int k = 0; k < K_SZ; ++k) {
      float d = kap[k] - cf;
      s += al[k] * exp2f(bn[k] * d * d);
    }
    phi_s[c] = s;
    out_phi[(size_t)b * C_SZ + c] = s;
  }
  // ---- exact zeros for c >= CL ----
  {
    float4 z = make_float4(0.f, 0.f, 0.f, 0.f);
    float4* po = (float4*)(out_phi + (size_t)b * C_SZ);
    for (int i = (CL >> 2) + tid; i < C_SZ / 4; i += 512) po[i] = z;
  }
  __syncthreads();

  // ---- window over [0, CL) rows of text ----
  const float4* __restrict__ t4 =
      (const float4*)(text + (size_t)b * C_SZ * A_SZ);
  const int a4 = tid & 31;   // float4 column (covers A=128)
  const int cr = tid >> 5;   // 16 parallel c-rows

  float4 acc = make_float4(0.f, 0.f, 0.f, 0.f);
  for (int cc = cr; cc < CL; cc += 16) {
    float p = phi_s[cc];
    float4 t = t4[cc * 32 + a4];       // coalesced 512B per row
    acc.x = fmaf(p, t.x, acc.x);
    acc.y = fmaf(p, t.y, acc.y);
    acc.z = fmaf(p, t.z, acc.z);
    acc.w = fmaf(p, t.w, acc.w);
  }

  red[cr][a4] = acc;
  __syncthreads();

  if (tid < 32) {
    float4 w = red[0][tid];
#pragma unroll
    for (int i = 1; i < 16; ++i) {
      float4 r = red[i][tid];
      w.x += r.x; w.y += r.y; w.z += r.z; w.w += r.w;
    }
    ((float4*)(out_window + (size_t)b * A_SZ))[tid] = w;
  }
}

extern "C" void kernel_launch(void* const* d_in, const int* in_sizes, int n_in,
                              void* d_out, int out_size, void* d_ws, size_t ws_size,
                              hipStream_t stream) {
  const float* x    = (const float*)d_in[0];
  const float* text = (const float*)d_in[1];
  const float* pk   = (const float*)d_in[2];
  const float* Wa   = (const float*)d_in[3];
  const float* ba   = (const float*)d_in[4];
  const float* Wb   = (const float*)d_in[5];
  const float* bb   = (const float*)d_in[6];
  const float* Wk   = (const float*)d_in[7];
  const float* bk   = (const float*)d_in[8];

  float* out        = (float*)d_out;
  float* out_phi    = out;                              // B*C
  float* out_kappa  = out + (size_t)B_SZ * C_SZ;        // B*K
  float* out_win    = out_kappa + (size_t)B_SZ * K_SZ;  // B*A

  float* ws         = (float*)d_ws;
  float* ws_alpha   = ws;
  float* ws_beta    = ws + (size_t)B_SZ * K_SZ;
  float* ws_kappa   = ws + (size_t)2 * B_SZ * K_SZ;

  gw_abk<<<B_SZ / 4, 768, 0, stream>>>(x, pk, Wa, ba, Wb, bb, Wk, bk,
                                       ws_alpha, ws_beta, ws_kappa, out_kappa);
  gw_phi_window<<<B_SZ, 512, 0, stream>>>(text, ws_alpha, ws_beta, ws_kappa,
                                          out_phi, out_win);
}

// Round 8
// 21.348 us; speedup vs baseline: 1.1025x; 1.1025x over previous
//
#include <hip/hip_runtime.h>

#define B_SZ 512
#define V_SZ 1024
#define K_SZ 64
#define C_SZ 2048
#define A_SZ 128

#define LOG2E 1.4426950408889634f

// ---------------------------------------------------------------------------
// Fully fused: one block per 2 batch rows, 768 threads (12 waves).
// Phase 1 (R6-validated GEMM): wave w -> matrix m=w>>2, v-quarter q=w&3;
//   one W-stream per wave, x-row-pair as float2 in LDS, LDS reduce.
//   alpha/beta/kappa go straight to LDS (only new_kappa written out).
// Phase 2 (R4-validated cutoff+phi+window): thread halves (384 each, wave-
//   aligned) own one row each: conservative cutoff CL (term <= 2^-150),
//   phi -> LDS+global, exact zeros beyond, window = phi[0:CL) @ text[0:CL).
// ---------------------------------------------------------------------------
__global__ __launch_bounds__(768) void gw_fused(
    const float* __restrict__ x, const float* __restrict__ text,
    const float* __restrict__ prev_kappa,
    const float* __restrict__ Wa, const float* __restrict__ ba,
    const float* __restrict__ Wb, const float* __restrict__ bb,
    const float* __restrict__ Wk, const float* __restrict__ bk,
    float* __restrict__ out_phi, float* __restrict__ out_kappa,
    float* __restrict__ out_window) {
  __shared__ float2 xs2[V_SZ];            // 8KB  {row0[v], row1[v]}
  __shared__ float part[12][2][K_SZ];     // 6KB  [wave][row][k]
  __shared__ float al[2][K_SZ];
  __shared__ float bn[2][K_SZ];           // -log2(e)*beta
  __shared__ float kap[2][K_SZ];
  __shared__ float bnd[2][K_SZ];
  __shared__ int cl_s[2];
  __shared__ float phi_s[2][C_SZ];        // 16KB
  __shared__ float4 red[2][12][32];       // 12KB

  const int tid = threadIdx.x;
  const int b0 = blockIdx.x * 2;

  // ---- stage x row pair ----
  {
    const float* x0 = x + (size_t)b0 * V_SZ;
    const float* x1 = x0 + V_SZ;
    for (int i = tid; i < V_SZ; i += 768)
      xs2[i] = make_float2(x0[i], x1[i]);   // coalesced sweeps
  }
  __syncthreads();

  // ---- Phase 1: GEMM (R6 structure, verbatim) ----
  {
    const int w = tid >> 6;     // wave 0..11
    const int m = w >> 2;       // 0=alpha, 1=beta, 2=kappa
    const int q = w & 3;        // v-quarter
    const int k = tid & 63;
    const float* __restrict__ Wm = (m == 0) ? Wa : (m == 1) ? Wb : Wk;

    float acc0 = 0.f, acc1 = 0.f;
    const int v0 = q * 256;
#pragma unroll 16
    for (int v = v0; v < v0 + 256; ++v) {
      float wv = Wm[v * K_SZ + k];    // 256B coalesced, single stream
      float2 xv = xs2[v];             // one ds_read_b64, wave-uniform addr
      acc0 = fmaf(xv.x, wv, acc0);
      acc1 = fmaf(xv.y, wv, acc1);
    }
    part[w][0][k] = acc0;
    part[w][1][k] = acc1;
  }
  __syncthreads();

  if (tid < 384) {
    const int mm = tid >> 7;         // 0=alpha, 1=beta, 2=kappa
    const int r = (tid >> 6) & 1;
    const int kk = tid & 63;
    float s = part[mm * 4 + 0][r][kk] + part[mm * 4 + 1][r][kk] +
              part[mm * 4 + 2][r][kk] + part[mm * 4 + 3][r][kk];
    const float bias = ((mm == 0) ? ba : (mm == 1) ? bb : bk)[kk];
    const float e = expf(s + bias);
    if (mm == 0) {
      al[r][kk] = e;
    } else if (mm == 1) {
      bn[r][kk] = -LOG2E * e;
    } else {
      float nk = prev_kappa[(b0 + r) * K_SZ + kk] + e;
      kap[r][kk] = nk;
      out_kappa[(b0 + r) * K_SZ + kk] = nk;
    }
  }
  __syncthreads();

  // ---- cutoff per row: term <= 2^-150 for c >= bnd ----
  if (tid < 128) {
    const int r = tid >> 6, kk = tid & 63;
    float num = 150.f + fmaxf(0.f, log2f(al[r][kk]));
    bnd[r][kk] = kap[r][kk] + sqrtf(num / (-bn[r][kk]));
  }
  __syncthreads();
  if (tid < 2) {
    float mx = 0.f;
    for (int i = 0; i < K_SZ; ++i) mx = fmaxf(mx, bnd[tid][i]);
    mx = fminf(mx, (float)C_SZ);     // sanitizes inf -> full compute
    int cl = (int)mx + 1;
    cl = (cl + 15) & ~15;
    if (cl > C_SZ) cl = C_SZ;
    cl_s[tid] = cl;
  }
  __syncthreads();

  // ---- Phase 2: halves (wave-aligned) own one row each ----
  const int half = tid / 384;        // 0 or 1
  const int t2 = tid - half * 384;   // 0..383
  const int r = half;
  const int b = b0 + r;
  const int CL = cl_s[r];

  // phi for c < CL
  for (int c = t2; c < CL; c += 384) {
    float cf = (float)c;
    float s = 0.f;
#pragma unroll
    for (int kk = 0; kk < K_SZ; ++kk) {
      float d = kap[r][kk] - cf;
      s += al[r][kk] * exp2f(bn[r][kk] * d * d);
    }
    phi_s[r][c] = s;
    out_phi[(size_t)b * C_SZ + c] = s;
  }
  // exact zeros for c >= CL
  {
    float4 z = make_float4(0.f, 0.f, 0.f, 0.f);
    float4* po = (float4*)(out_phi + (size_t)b * C_SZ);
    for (int i = (CL >> 2) + t2; i < C_SZ / 4; i += 384) po[i] = z;
  }
  __syncthreads();

  // window over [0, CL) rows of text
  {
    const float4* __restrict__ t4 =
        (const float4*)(text + (size_t)b * C_SZ * A_SZ);
    const int a4 = t2 & 31;   // float4 column (covers A=128)
    const int cr = t2 >> 5;   // 12 parallel c-rows per half

    float4 acc = make_float4(0.f, 0.f, 0.f, 0.f);
    for (int cc = cr; cc < CL; cc += 12) {
      float p = phi_s[r][cc];
      float4 t = t4[cc * 32 + a4];   // coalesced 512B per row
      acc.x = fmaf(p, t.x, acc.x);
      acc.y = fmaf(p, t.y, acc.y);
      acc.z = fmaf(p, t.z, acc.z);
      acc.w = fmaf(p, t.w, acc.w);
    }
    red[r][cr][a4] = acc;
  }
  __syncthreads();

  if (t2 < 32) {
    float4 wv = red[r][0][t2];
#pragma unroll
    for (int i = 1; i < 12; ++i) {
      float4 rr = red[r][i][t2];
      wv.x += rr.x; wv.y += rr.y; wv.z += rr.z; wv.w += rr.w;
    }
    ((float4*)(out_window + (size_t)b * A_SZ))[t2] = wv;
  }
}

extern "C" void kernel_launch(void* const* d_in, const int* in_sizes, int n_in,
                              void* d_out, int out_size, void* d_ws, size_t ws_size,
                              hipStream_t stream) {
  const float* x    = (const float*)d_in[0];
  const float* text = (const float*)d_in[1];
  const float* pk   = (const float*)d_in[2];
  const float* Wa   = (const float*)d_in[3];
  const float* ba   = (const float*)d_in[4];
  const float* Wb   = (const float*)d_in[5];
  const float* bb   = (const float*)d_in[6];
  const float* Wk   = (const float*)d_in[7];
  const float* bk   = (const float*)d_in[8];

  float* out        = (float*)d_out;
  float* out_phi    = out;                              // B*C
  float* out_kappa  = out + (size_t)B_SZ * C_SZ;        // B*K
  float* out_win    = out_kappa + (size_t)B_SZ * K_SZ;  // B*A

  gw_fused<<<B_SZ / 2, 768, 0, stream>>>(x, text, pk, Wa, ba, Wb, bb, Wk, bk,
                                         out_phi, out_kappa, out_win);
}